// Round 4
// baseline (462.139 us; speedup 1.0000x reference)
//
#include <hip/hip_runtime.h>
#include <math.h>

// AdaptivePatchEmbedding — MI355X, round 4 (resubmission of r3; r3 never ran:
// GPU acquisition timeout. r2's compile error fixed via ext_vector_type(4)).
// Structure: single-selected-expert collapse (ST gumbel one-hot is exact in
// fp32), patch dedup per repeat_idx, fp64 pos-emb table in d_ws,
// 16B/lane nontemporal streaming stores.
//
// Output layout (float, concatenated in reference return order):
//   [0 .. XP_ELEMS)                      x_patch  [4096, 42, 512]
//   [XP_ELEMS]                           C = 32
//   [XP_ELEMS+1 .. XP_ELEMS+1+R*N)       cls_pred (region-major: r*N + n)

namespace {
constexpr int NROWS = 4096;   // B*C
constexpr int SEQ   = 336;
constexpr int RREG  = 7;      // regions per row (336/48)
constexpr int TGT   = 6;      // target patches per region
constexpr int DM    = 512;
constexpr int DM4   = DM / 4; // 128 vec4 per row
constexpr int NEXP  = 4;
constexpr long long XP_ELEMS = (long long)NROWS * RREG * TGT * DM; // 88,080,384
constexpr int PE_ELEMS = RREG * TGT * DM;                          // 21,504
}

typedef float v4f __attribute__((ext_vector_type(4)));

// Positional embedding, computed in double to match numpy float64 -> float32.
__global__ void pe_kernel(float* __restrict__ pe) {
    int i = blockIdx.x * blockDim.x + threadIdx.x;
    if (i >= PE_ELEMS) return;
    int p = i / DM, d = i - p * DM;
    int j = d >> 1;
    double div = exp((double)(2 * j) * -(log(10000.0) / (double)DM));
    double a = (double)p * div;
    pe[i] = (d & 1) ? (float)cos(a) : (float)sin(a);
}

// Fallback float pos-emb (only if ws too small to hold the table).
__device__ inline float pe_val(int p, int d) {
    int j = d >> 1;
    float div = __expf((float)(2 * j) * (-9.210340371976184f / 512.0f));
    float a = (float)p * div;
    return (d & 1) ? __cosf(a) : __sinf(a);
}

template <bool HAVE_PE>
__global__ __launch_bounds__(256) void apk_kernel(
    const float* __restrict__ x,   const float* __restrict__ un,
    const float* __restrict__ W1,  const float* __restrict__ b1,
    const float* __restrict__ W2,  const float* __restrict__ b2,
    const float* __restrict__ We0, const float* __restrict__ We1,
    const float* __restrict__ We2, const float* __restrict__ We3,
    const float* __restrict__ pe,  float* __restrict__ out)
{
    const int blk = blockIdx.x;            // 0 .. NROWS*RREG-1
    const int n = blk / RREG;
    const int r = blk - n * RREG;
    const int tid = threadIdx.x;

    __shared__ float sx[48];
    __shared__ float sh[64];
    __shared__ float sz[NEXP];
    __shared__ float s_w;
    __shared__ int   s_e;

    // --- stage region x into LDS ---
    if (tid < 48) sx[tid] = x[(size_t)n * SEQ + r * 48 + tid];
    __syncthreads();

    // --- router MLP hidden layer: 48 -> 64, relu ---
    if (tid < 64) {
        float h = b1[tid];
        #pragma unroll
        for (int k = 0; k < 48; ++k) h = fmaf(sx[k], W1[k * 64 + tid], h);
        sh[tid] = fmaxf(h, 0.0f);
    }
    __syncthreads();

    // --- logits + gumbel, scaled by 1/tau ---
    if (tid < NEXP) {
        float z = b2[tid];
        #pragma unroll
        for (int j = 0; j < 64; ++j) z = fmaf(sh[j], W2[j * NEXP + tid], z);
        float uu = un[(size_t)blk * NEXP + tid];
        float g = -logf(-logf(uu + 1e-10f) + 1e-10f);
        sz[tid] = (z + g) / 0.5f;
    }
    __syncthreads();

    // --- argmax + straight-through weight w = (1+s)-s ---
    if (tid == 0) {
        float z0 = sz[0], z1 = sz[1], z2 = sz[2], z3 = sz[3];
        int e = 0; float zm = z0;
        if (z1 > zm) { zm = z1; e = 1; }
        if (z2 > zm) { zm = z2; e = 2; }
        if (z3 > zm) { zm = z3; e = 3; }
        float s = 1.0f / (((expf(z0 - zm) + expf(z1 - zm)) + expf(z2 - zm)) + expf(z3 - zm));
        s_e = e;
        s_w = (1.0f + s) - s;
        out[(size_t)XP_ELEMS + 1 + (size_t)r * NROWS + n] = (float)e;  // cls_pred
        if (blk == 0) out[(size_t)XP_ELEMS] = 32.0f;                    // C
    }
    __syncthreads();

    const int e = s_e;            // uniform across block -> no divergence
    const float w = s_w;
    const int c4   = tid & 127;   // vec4 column index within a row
    const int half = tid >> 7;    // 0: rows {0,2,4}; 1: rows {1,3,5}
    v4f* __restrict__ outv = reinterpret_cast<v4f*>(out);
    const v4f* __restrict__ pev = reinterpret_cast<const v4f*>(pe);
    const size_t ob = ((size_t)n * (RREG * TGT) + (size_t)r * TGT) * DM4;
    const int pb = r * TGT * DM4;

    auto pe4 = [&](int t) -> v4f {
        if constexpr (HAVE_PE) {
            return pev[pb + t * DM4 + c4];
        } else {
            v4f v;
            v.x = pe_val(r * TGT + t, 4 * c4 + 0);
            v.y = pe_val(r * TGT + t, 4 * c4 + 1);
            v.z = pe_val(r * TGT + t, 4 * c4 + 2);
            v.w = pe_val(r * TGT + t, 4 * c4 + 3);
            return v;
        }
    };
    auto emit = [&](int t, const v4f& a) {
        v4f pv = pe4(t);
        v4f v;
        v.x = fmaf(a.x, w, pv.x);
        v.y = fmaf(a.y, w, pv.y);
        v.z = fmaf(a.z, w, pv.z);
        v.w = fmaf(a.w, w, pv.w);
        __builtin_nontemporal_store(v, &outv[ob + (size_t)t * DM4 + c4]);
    };
    auto fma4 = [](float xv, const v4f& wv, v4f& a) {
        a.x = fmaf(xv, wv.x, a.x);
        a.y = fmaf(xv, wv.y, a.y);
        a.z = fmaf(xv, wv.z, a.z);
        a.w = fmaf(xv, wv.w, a.w);
    };
    const v4f zero4 = (v4f)(0.0f);

    if (e == 0) {
        // plen=8: patch map t->t. This thread's rows: t_i = half + 2*i.
        const v4f* W = reinterpret_cast<const v4f*>(We0);
        v4f a0 = zero4, a1 = zero4, a2 = zero4;
        #pragma unroll
        for (int k = 0; k < 8; ++k) {
            v4f wv = W[k * DM4 + c4];
            fma4(sx[(half + 0) * 8 + k], wv, a0);
            fma4(sx[(half + 2) * 8 + k], wv, a1);
            fma4(sx[(half + 4) * 8 + k], wv, a2);
        }
        emit(half + 0, a0);
        emit(half + 2, a1);
        emit(half + 4, a2);
    } else if (e == 1) {
        // plen=16: patch map [0,0,0,0,1,1]
        const v4f* W = reinterpret_cast<const v4f*>(We1);
        v4f a0 = zero4, a1 = zero4;
        #pragma unroll
        for (int k = 0; k < 16; ++k) {
            v4f wv = W[k * DM4 + c4];
            fma4(sx[k],      wv, a0);
            fma4(sx[16 + k], wv, a1);
        }
        #pragma unroll
        for (int i = 0; i < 3; ++i) {
            int t = half + 2 * i;
            emit(t, (t < 4) ? a0 : a1);
        }
    } else if (e == 2) {
        // plen=24: patch map [0,0,0,0,0,1]
        const v4f* W = reinterpret_cast<const v4f*>(We2);
        v4f a0 = zero4, a1 = zero4;
        #pragma unroll
        for (int k = 0; k < 24; ++k) {
            v4f wv = W[k * DM4 + c4];
            fma4(sx[k],      wv, a0);
            fma4(sx[24 + k], wv, a1);
        }
        #pragma unroll
        for (int i = 0; i < 3; ++i) {
            int t = half + 2 * i;
            emit(t, (t < 5) ? a0 : a1);
        }
    } else {
        // plen=48: single distinct patch
        const v4f* W = reinterpret_cast<const v4f*>(We3);
        v4f a0 = zero4;
        #pragma unroll
        for (int k = 0; k < 48; ++k) {
            v4f wv = W[k * DM4 + c4];
            fma4(sx[k], wv, a0);
        }
        #pragma unroll
        for (int i = 0; i < 3; ++i) emit(half + 2 * i, a0);
    }
}

extern "C" void kernel_launch(void* const* d_in, const int* in_sizes, int n_in,
                              void* d_out, int out_size, void* d_ws, size_t ws_size,
                              hipStream_t stream) {
    const float* x   = (const float*)d_in[0];
    const float* un  = (const float*)d_in[1];
    const float* W1  = (const float*)d_in[2];
    const float* b1  = (const float*)d_in[3];
    const float* W2  = (const float*)d_in[4];
    const float* b2  = (const float*)d_in[5];
    const float* We0 = (const float*)d_in[6];
    const float* We1 = (const float*)d_in[7];
    const float* We2 = (const float*)d_in[8];
    const float* We3 = (const float*)d_in[9];
    float* out = (float*)d_out;

    const int nblk = NROWS * RREG;  // 28,672
    const bool have_pe = ws_size >= (size_t)PE_ELEMS * sizeof(float);

    if (have_pe) {
        float* pe = (float*)d_ws;
        pe_kernel<<<(PE_ELEMS + 255) / 256, 256, 0, stream>>>(pe);
        apk_kernel<true><<<nblk, 256, 0, stream>>>(
            x, un, W1, b1, W2, b2, We0, We1, We2, We3, pe, out);
    } else {
        apk_kernel<false><<<nblk, 256, 0, stream>>>(
            x, un, W1, b1, W2, b2, We0, We1, We2, We3, (const float*)nullptr, out);
    }
}

// Round 5
// 446.163 us; speedup vs baseline: 1.0358x; 1.0358x over previous
//
#include <hip/hip_runtime.h>
#include <math.h>

// AdaptivePatchEmbedding — MI355X, round 5.
// r4 passed at 462 us but Occupancy=12.5% (exactly 1 block/CU): block
// lifetime dominated by the serial router head (5 syncs, 48/64/4/1-lane
// phases); store phase starved. Split: router_kernel (1 thread/region,
// no LDS/sync) -> (w,e) in d_ws; embed_kernel (1 block/region, 0 syncs,
// all lanes active, NT float4 stores). Numerics identical to r4.
//
// Output layout (float, concatenated in reference return order):
//   [0 .. XP_ELEMS)                      x_patch  [4096, 42, 512]
//   [XP_ELEMS]                           C = 32
//   [XP_ELEMS+1 .. XP_ELEMS+1+R*N)       cls_pred (region-major: r*N + n)
//
// ws layout (floats): [0, 21504) pe table | [21504, 21504+2*28672) (w,e) pairs

namespace {
constexpr int NROWS = 4096;   // B*C
constexpr int SEQ   = 336;
constexpr int RREG  = 7;      // regions per row
constexpr int TGT   = 6;
constexpr int DM    = 512;
constexpr int DM4   = DM / 4;
constexpr int NEXP  = 4;
constexpr int NREG  = NROWS * RREG;                                // 28672
constexpr long long XP_ELEMS = (long long)NROWS * RREG * TGT * DM; // 88,080,384
constexpr int PE_ELEMS = RREG * TGT * DM;                          // 21504
constexpr size_t WS_FLOATS = (size_t)PE_ELEMS + (size_t)NREG * 2;
}

typedef float v4f __attribute__((ext_vector_type(4)));
typedef float v2f __attribute__((ext_vector_type(2)));

// Positional embedding, computed in double to match numpy float64 -> float32.
__global__ void pe_kernel(float* __restrict__ pe) {
    int i = blockIdx.x * blockDim.x + threadIdx.x;
    if (i >= PE_ELEMS) return;
    int p = i / DM, d = i - p * DM;
    int j = d >> 1;
    double div = exp((double)(2 * j) * -(log(10000.0) / (double)DM));
    double a = (double)p * div;
    pe[i] = (d & 1) ? (float)cos(a) : (float)sin(a);
}

// Fallback float pos-emb (only for the fused fallback path).
__device__ inline float pe_val(int p, int d) {
    int j = d >> 1;
    float div = __expf((float)(2 * j) * (-9.210340371976184f / 512.0f));
    float a = (float)p * div;
    return (d & 1) ? __cosf(a) : __sinf(a);
}

// ---------------- router: one thread per region ----------------
__global__ __launch_bounds__(256) void router_kernel(
    const float* __restrict__ x,  const float* __restrict__ un,
    const float* __restrict__ W1, const float* __restrict__ b1,
    const float* __restrict__ W2, const float* __restrict__ b2,
    v2f* __restrict__ ew, float* __restrict__ out)
{
    const int g = blockIdx.x * 256 + threadIdx.x;
    if (g >= NREG) return;
    const int n = g / RREG, r = g - n * RREG;

    float xv[48];
    const v4f* xr4 = reinterpret_cast<const v4f*>(x + (size_t)n * SEQ + r * 48);
    #pragma unroll
    for (int i = 0; i < 12; ++i) {
        v4f v = xr4[i];
        xv[4 * i + 0] = v.x; xv[4 * i + 1] = v.y;
        xv[4 * i + 2] = v.z; xv[4 * i + 3] = v.w;
    }

    // logits (same fmaf order as the r4 kernel: h over k asc, z over j asc)
    float z0 = b2[0], z1 = b2[1], z2 = b2[2], z3 = b2[3];
    for (int j = 0; j < 64; ++j) {
        float h = b1[j];
        #pragma unroll
        for (int k = 0; k < 48; ++k) h = fmaf(xv[k], W1[k * 64 + j], h);
        h = fmaxf(h, 0.0f);
        z0 = fmaf(h, W2[j * NEXP + 0], z0);
        z1 = fmaf(h, W2[j * NEXP + 1], z1);
        z2 = fmaf(h, W2[j * NEXP + 2], z2);
        z3 = fmaf(h, W2[j * NEXP + 3], z3);
    }

    const float* ug = un + (size_t)g * NEXP;
    z0 = (z0 + -logf(-logf(ug[0] + 1e-10f) + 1e-10f)) / 0.5f;
    z1 = (z1 + -logf(-logf(ug[1] + 1e-10f) + 1e-10f)) / 0.5f;
    z2 = (z2 + -logf(-logf(ug[2] + 1e-10f) + 1e-10f)) / 0.5f;
    z3 = (z3 + -logf(-logf(ug[3] + 1e-10f) + 1e-10f)) / 0.5f;

    int e = 0; float zm = z0;
    if (z1 > zm) { zm = z1; e = 1; }
    if (z2 > zm) { zm = z2; e = 2; }
    if (z3 > zm) { zm = z3; e = 3; }
    float s = 1.0f / (((expf(z0 - zm) + expf(z1 - zm)) + expf(z2 - zm)) + expf(z3 - zm));
    float w = (1.0f + s) - s;

    v2f p; p.x = w; p.y = (float)e;
    ew[g] = p;
    out[(size_t)XP_ELEMS + 1 + (size_t)r * NROWS + n] = (float)e;  // cls_pred
    if (g == 0) out[(size_t)XP_ELEMS] = 32.0f;                      // C
}

// ---------------- embed: one block per region, no syncs ----------------
__global__ __launch_bounds__(256) void embed_kernel(
    const float* __restrict__ x,   const v2f* __restrict__ ew,
    const float* __restrict__ We0, const float* __restrict__ We1,
    const float* __restrict__ We2, const float* __restrict__ We3,
    const float* __restrict__ pe,  float* __restrict__ out)
{
    const int blk = blockIdx.x;
    const int n = blk / RREG;
    const int r = blk - n * RREG;
    const int tid = threadIdx.x;

    const v2f ewv = ew[blk];           // uniform broadcast
    const float w = ewv.x;
    const int e = (int)ewv.y;          // uniform -> no divergence
    const float* __restrict__ xr = x + (size_t)n * SEQ + r * 48;  // uniform loads

    const int c4   = tid & 127;   // vec4 column index within a row
    const int half = tid >> 7;    // 0: rows {0,2,4}; 1: rows {1,3,5}
    v4f* __restrict__ outv = reinterpret_cast<v4f*>(out);
    const v4f* __restrict__ pev = reinterpret_cast<const v4f*>(pe);
    const size_t ob = ((size_t)n * (RREG * TGT) + (size_t)r * TGT) * DM4;
    const int pb = r * TGT * DM4;

    auto emit = [&](int t, const v4f& a) {
        v4f pv = pev[pb + t * DM4 + c4];
        v4f v;
        v.x = fmaf(a.x, w, pv.x);
        v.y = fmaf(a.y, w, pv.y);
        v.z = fmaf(a.z, w, pv.z);
        v.w = fmaf(a.w, w, pv.w);
        __builtin_nontemporal_store(v, &outv[ob + (size_t)t * DM4 + c4]);
    };
    auto fma4 = [](float xvv, const v4f& wv, v4f& a) {
        a.x = fmaf(xvv, wv.x, a.x);
        a.y = fmaf(xvv, wv.y, a.y);
        a.z = fmaf(xvv, wv.z, a.z);
        a.w = fmaf(xvv, wv.w, a.w);
    };
    const v4f zero4 = (v4f)(0.0f);

    if (e == 0) {
        // plen=8: patch map t->t; this thread's rows t_i = half + 2*i
        const v4f* W = reinterpret_cast<const v4f*>(We0);
        v4f a0 = zero4, a1 = zero4, a2 = zero4;
        #pragma unroll
        for (int k = 0; k < 8; ++k) {
            v4f wv = W[k * DM4 + c4];
            fma4(xr[(half + 0) * 8 + k], wv, a0);
            fma4(xr[(half + 2) * 8 + k], wv, a1);
            fma4(xr[(half + 4) * 8 + k], wv, a2);
        }
        emit(half + 0, a0);
        emit(half + 2, a1);
        emit(half + 4, a2);
    } else if (e == 1) {
        // plen=16: patch map [0,0,0,0,1,1]
        const v4f* W = reinterpret_cast<const v4f*>(We1);
        v4f a0 = zero4, a1 = zero4;
        #pragma unroll
        for (int k = 0; k < 16; ++k) {
            v4f wv = W[k * DM4 + c4];
            fma4(xr[k],      wv, a0);
            fma4(xr[16 + k], wv, a1);
        }
        #pragma unroll
        for (int i = 0; i < 3; ++i) {
            int t = half + 2 * i;
            emit(t, (t < 4) ? a0 : a1);
        }
    } else if (e == 2) {
        // plen=24: patch map [0,0,0,0,0,1]
        const v4f* W = reinterpret_cast<const v4f*>(We2);
        v4f a0 = zero4, a1 = zero4;
        #pragma unroll
        for (int k = 0; k < 24; ++k) {
            v4f wv = W[k * DM4 + c4];
            fma4(xr[k],      wv, a0);
            fma4(xr[24 + k], wv, a1);
        }
        #pragma unroll
        for (int i = 0; i < 3; ++i) {
            int t = half + 2 * i;
            emit(t, (t < 5) ? a0 : a1);
        }
    } else {
        // plen=48: single distinct patch
        const v4f* W = reinterpret_cast<const v4f*>(We3);
        v4f a0 = zero4;
        #pragma unroll
        for (int k = 0; k < 48; ++k) {
            v4f wv = W[k * DM4 + c4];
            fma4(xr[k], wv, a0);
        }
        #pragma unroll
        for (int i = 0; i < 3; ++i) emit(half + 2 * i, a0);
    }
}

// ---------------- fallback: fused r4-style kernel (ws too small) ----------------
__global__ __launch_bounds__(256) void apk_fused_kernel(
    const float* __restrict__ x,   const float* __restrict__ un,
    const float* __restrict__ W1,  const float* __restrict__ b1,
    const float* __restrict__ W2,  const float* __restrict__ b2,
    const float* __restrict__ We0, const float* __restrict__ We1,
    const float* __restrict__ We2, const float* __restrict__ We3,
    float* __restrict__ out)
{
    const int blk = blockIdx.x;
    const int n = blk / RREG;
    const int r = blk - n * RREG;
    const int tid = threadIdx.x;

    __shared__ float sx[48];
    __shared__ float sh[64];
    __shared__ float sz[NEXP];
    __shared__ float s_w;
    __shared__ int   s_e;

    if (tid < 48) sx[tid] = x[(size_t)n * SEQ + r * 48 + tid];
    __syncthreads();
    if (tid < 64) {
        float h = b1[tid];
        #pragma unroll
        for (int k = 0; k < 48; ++k) h = fmaf(sx[k], W1[k * 64 + tid], h);
        sh[tid] = fmaxf(h, 0.0f);
    }
    __syncthreads();
    if (tid < NEXP) {
        float z = b2[tid];
        #pragma unroll
        for (int j = 0; j < 64; ++j) z = fmaf(sh[j], W2[j * NEXP + tid], z);
        float uu = un[(size_t)blk * NEXP + tid];
        float g = -logf(-logf(uu + 1e-10f) + 1e-10f);
        sz[tid] = (z + g) / 0.5f;
    }
    __syncthreads();
    if (tid == 0) {
        float z0 = sz[0], z1 = sz[1], z2 = sz[2], z3 = sz[3];
        int e = 0; float zm = z0;
        if (z1 > zm) { zm = z1; e = 1; }
        if (z2 > zm) { zm = z2; e = 2; }
        if (z3 > zm) { zm = z3; e = 3; }
        float s = 1.0f / (((expf(z0 - zm) + expf(z1 - zm)) + expf(z2 - zm)) + expf(z3 - zm));
        s_e = e;
        s_w = (1.0f + s) - s;
        out[(size_t)XP_ELEMS + 1 + (size_t)r * NROWS + n] = (float)e;
        if (blk == 0) out[(size_t)XP_ELEMS] = 32.0f;
    }
    __syncthreads();

    const int e = s_e;
    const float w = s_w;
    const int c4   = tid & 127;
    const int half = tid >> 7;
    v4f* __restrict__ outv = reinterpret_cast<v4f*>(out);
    const size_t ob = ((size_t)n * (RREG * TGT) + (size_t)r * TGT) * DM4;

    auto pe4 = [&](int t) -> v4f {
        v4f v;
        v.x = pe_val(r * TGT + t, 4 * c4 + 0);
        v.y = pe_val(r * TGT + t, 4 * c4 + 1);
        v.z = pe_val(r * TGT + t, 4 * c4 + 2);
        v.w = pe_val(r * TGT + t, 4 * c4 + 3);
        return v;
    };
    auto emit = [&](int t, const v4f& a) {
        v4f pv = pe4(t);
        v4f v;
        v.x = fmaf(a.x, w, pv.x);
        v.y = fmaf(a.y, w, pv.y);
        v.z = fmaf(a.z, w, pv.z);
        v.w = fmaf(a.w, w, pv.w);
        __builtin_nontemporal_store(v, &outv[ob + (size_t)t * DM4 + c4]);
    };
    auto fma4 = [](float xv, const v4f& wv, v4f& a) {
        a.x = fmaf(xv, wv.x, a.x);
        a.y = fmaf(xv, wv.y, a.y);
        a.z = fmaf(xv, wv.z, a.z);
        a.w = fmaf(xv, wv.w, a.w);
    };
    const v4f zero4 = (v4f)(0.0f);

    if (e == 0) {
        const v4f* W = reinterpret_cast<const v4f*>(We0);
        v4f a0 = zero4, a1 = zero4, a2 = zero4;
        #pragma unroll
        for (int k = 0; k < 8; ++k) {
            v4f wv = W[k * DM4 + c4];
            fma4(sx[(half + 0) * 8 + k], wv, a0);
            fma4(sx[(half + 2) * 8 + k], wv, a1);
            fma4(sx[(half + 4) * 8 + k], wv, a2);
        }
        emit(half + 0, a0); emit(half + 2, a1); emit(half + 4, a2);
    } else if (e == 1) {
        const v4f* W = reinterpret_cast<const v4f*>(We1);
        v4f a0 = zero4, a1 = zero4;
        #pragma unroll
        for (int k = 0; k < 16; ++k) {
            v4f wv = W[k * DM4 + c4];
            fma4(sx[k], wv, a0); fma4(sx[16 + k], wv, a1);
        }
        #pragma unroll
        for (int i = 0; i < 3; ++i) { int t = half + 2 * i; emit(t, (t < 4) ? a0 : a1); }
    } else if (e == 2) {
        const v4f* W = reinterpret_cast<const v4f*>(We2);
        v4f a0 = zero4, a1 = zero4;
        #pragma unroll
        for (int k = 0; k < 24; ++k) {
            v4f wv = W[k * DM4 + c4];
            fma4(sx[k], wv, a0); fma4(sx[24 + k], wv, a1);
        }
        #pragma unroll
        for (int i = 0; i < 3; ++i) { int t = half + 2 * i; emit(t, (t < 5) ? a0 : a1); }
    } else {
        const v4f* W = reinterpret_cast<const v4f*>(We3);
        v4f a0 = zero4;
        #pragma unroll
        for (int k = 0; k < 48; ++k) { v4f wv = W[k * DM4 + c4]; fma4(sx[k], wv, a0); }
        #pragma unroll
        for (int i = 0; i < 3; ++i) emit(half + 2 * i, a0);
    }
}

extern "C" void kernel_launch(void* const* d_in, const int* in_sizes, int n_in,
                              void* d_out, int out_size, void* d_ws, size_t ws_size,
                              hipStream_t stream) {
    const float* x   = (const float*)d_in[0];
    const float* un  = (const float*)d_in[1];
    const float* W1  = (const float*)d_in[2];
    const float* b1  = (const float*)d_in[3];
    const float* W2  = (const float*)d_in[4];
    const float* b2  = (const float*)d_in[5];
    const float* We0 = (const float*)d_in[6];
    const float* We1 = (const float*)d_in[7];
    const float* We2 = (const float*)d_in[8];
    const float* We3 = (const float*)d_in[9];
    float* out = (float*)d_out;

    if (ws_size >= WS_FLOATS * sizeof(float)) {
        float* pe = (float*)d_ws;
        v2f* ew = reinterpret_cast<v2f*>((float*)d_ws + PE_ELEMS);
        pe_kernel<<<(PE_ELEMS + 255) / 256, 256, 0, stream>>>(pe);
        router_kernel<<<(NREG + 255) / 256, 256, 0, stream>>>(
            x, un, W1, b1, W2, b2, ew, out);
        embed_kernel<<<NREG, 256, 0, stream>>>(
            x, ew, We0, We1, We2, We3, pe, out);
    } else {
        apk_fused_kernel<<<NREG, 256, 0, stream>>>(
            x, un, W1, b1, W2, b2, We0, We1, We2, We3, out);
    }
}